// Round 13
// baseline (85.741 us; speedup 1.0000x reference)
//
#include <hip/hip_runtime.h>
#include <hip/hip_bf16.h>
#include <math.h>

#define NROWS 8192
#define HALF_N 4096
#define KD 512
#define TILE 128
#define BK 64                     // i8: 64 B per row per K-tile
#define NKT 8                     // KD / BK
#define INV_Q2 (2.0f / 16129.0f)  // TEMP_INV / 127^2
#define NTRI 2080

typedef __attribute__((ext_vector_type(4))) int i32x4;

// Kernel 1: row-normalize f32 -> int8 (q = round(127*x/||x||)), zero accums.
__global__ __launch_bounds__(256) void normalize_kernel(const float* __restrict__ X,
                                                        signed char* __restrict__ XN8,
                                                        float* __restrict__ sumexp,
                                                        float* __restrict__ out) {
    const int row = blockIdx.x;
    const int tid = threadIdx.x;
    const int gz = row * 256 + tid;
    if (gz < NROWS) sumexp[gz] = 0.0f;
    if (gz == 0) out[0] = 0.0f;

    const float2 v = reinterpret_cast<const float2*>(X + (size_t)row * KD)[tid];
    float ss = v.x * v.x + v.y * v.y;
    #pragma unroll
    for (int off = 32; off >= 1; off >>= 1) ss += __shfl_xor(ss, off);
    __shared__ float wss[4];
    if ((tid & 63) == 0) wss[tid >> 6] = ss;
    __syncthreads();
    const float tot = wss[0] + wss[1] + wss[2] + wss[3];
    const float scale = 127.0f / fmaxf(sqrtf(tot), 1e-6f);
    char2 o;
    o.x = (signed char)__float2int_rn(v.x * scale);
    o.y = (signed char)__float2int_rn(v.y * scale);
    *reinterpret_cast<char2*>(XN8 + (size_t)row * KD + 2 * tid) = o;
}

#define SB __builtin_amdgcn_sched_barrier(0)

// Supertile decode (R7-proven): 4x4 grid of 16x16-block supertiles, bi <= bj.
__device__ __forceinline__ void decode_tri(int b, int& bi, int& bj) {
    const int pref[10] = {136, 392, 648, 904, 1040, 1296, 1552, 1688, 1944, 2080};
    const int sij[10]  = {0x00, 0x01, 0x02, 0x03, 0x11, 0x12, 0x13, 0x22, 0x23, 0x33};
    int st = 0;
    #pragma unroll
    for (int k = 0; k < 9; ++k) st += (b >= pref[k]);
    const int base = st ? pref[st - 1] : 0;
    const int L = b - base;
    const int si = sij[st] >> 4, sj = sij[st] & 15;
    int li, lj;
    if (si == sj) {
        li = (int)(16.5f - sqrtf(16.5f * 16.5f - 2.0f * (float)L));
        while ((li + 1) * (33 - (li + 1)) / 2 <= L) ++li;
        while (li * (33 - li) / 2 > L) --li;
        lj = li + (L - li * (33 - li) / 2);
    } else {
        li = L >> 4;
        lj = L & 15;
        if (li & 1) lj = 15 - lj;
    }
    bi = si * 16 + li;
    bj = sj * 16 + lj;
}

// Kernel 2: int8 128x128-tile GEMM (S ~ XN*XN^T / 127^2), ZERO-LDS /
// ZERO-BARRIER main loop. Each wave reads its A and B fragments directly from
// the L2-resident 4MB int8 table (16 contiguous B/lane, 16 rows x 64 B per
// instruction), double-buffered one tile ahead with per-wave vmcnt(8) flow
// control. Waves are fully decoupled -> stalls don't gang; occupancy is
// VGPR-bound (~12 indep waves/CU) instead of LDS-bound.
__global__ __launch_bounds__(256, 3) void gemm_fused_kernel(const signed char* __restrict__ XN8,
                                                            float* __restrict__ sumexp,
                                                            float* __restrict__ poslogit) {
    __shared__ float redbuf[2 * TILE];   // epilogue row/col sums only

    const int b = (blockIdx.x & 7) * (NTRI / 8) + (blockIdx.x >> 3);
    int bi, bj;
    decode_tri(b, bi, bj);

    const int rowBase = bi * TILE;
    const int colBase = bj * TILE;

    const int tid  = threadIdx.x;
    const int lane = tid & 63;
    const int wid  = tid >> 6;          // 0..3
    const int wr   = wid >> 1;          // 0/1  (64 output rows per wave)
    const int wc   = wid & 1;           // 0/1  (64 output cols per wave)
    const int l15  = lane & 15;
    const int l4   = lane >> 4;

    // Fragment pointers: lane (l15,l4) reads row base+m*16+l15, bytes l4*16..+16.
    // Waves sharing wr re-hit A lines in L1/L2; same for wc/B.
    const signed char* aP[4];
    const signed char* bP[4];
    #pragma unroll
    for (int m = 0; m < 4; ++m)
        aP[m] = XN8 + (size_t)(rowBase + wr * 64 + m * 16 + l15) * KD + l4 * 16;
    #pragma unroll
    for (int n = 0; n < 4; ++n)
        bP[n] = XN8 + (size_t)(colBase + wc * 64 + n * 16 + l15) * KD + l4 * 16;

#define LOADT(AA, BB, T) do {                                                  \
    _Pragma("unroll")                                                          \
    for (int m = 0; m < 4; ++m) AA[m] = *(const i32x4*)(aP[m] + (T) * BK);     \
    _Pragma("unroll")                                                          \
    for (int n = 0; n < 4; ++n) BB[n] = *(const i32x4*)(bP[n] + (T) * BK);     \
  } while (0)

// Phase T: wait tile T landed (vmcnt: 8 newer loads may stay in flight) |
// 16 MFMA | refill same buffer with tile T+2 (WAR: issued after MFMA reads).
#define PHR(T, AA, BB, V) do {                                                 \
    asm volatile("s_waitcnt vmcnt(" #V ")" ::: "memory");                      \
    SB;                                                                        \
    __builtin_amdgcn_s_setprio(1);                                             \
    _Pragma("unroll")                                                          \
    for (int m = 0; m < 4; ++m)                                                \
        _Pragma("unroll")                                                      \
        for (int n = 0; n < 4; ++n)                                            \
            acc[m][n] = __builtin_amdgcn_mfma_i32_16x16x64_i8(                 \
                AA[m], BB[n], acc[m][n], 0, 0, 0);                             \
    __builtin_amdgcn_s_setprio(0);                                             \
    SB;                                                                        \
    if ((T) + 2 < NKT) LOADT(AA, BB, (T) + 2);                                 \
    SB;                                                                        \
  } while (0)

    i32x4 acc[4][4] = {};
    i32x4 aE[4], bE[4], aO[4], bO[4];

    // Prologue: tiles 0 (even buf) and 1 (odd buf) in flight (16 loads).
    LOADT(aE, bE, 0);
    LOADT(aO, bO, 1);

    PHR(0, aE, bE, 8);
    PHR(1, aO, bO, 8);
    PHR(2, aE, bE, 8);
    PHR(3, aO, bO, 8);
    PHR(4, aE, bE, 8);
    PHR(5, aO, bO, 8);
    PHR(6, aE, bE, 8);
    PHR(7, aO, bO, 0);

    // Epilogue. C/D map: col = l15, row = l4*4 + reg. logit = acc * 2/127^2.
    // Universal rule (R11/R12-validated): count only gcol > grow; add to
    // rowsum AND colsum (diagonal tiles need no split; mirrors via colsum).
    float* rowsum = redbuf;               // [128]
    float* colsum = redbuf + TILE;        // [128]
    if (tid < TILE) { rowsum[tid] = 0.0f; colsum[tid] = 0.0f; }
    __syncthreads();

    float cs[4] = {0.0f, 0.0f, 0.0f, 0.0f};
    #pragma unroll
    for (int m = 0; m < 4; ++m) {
        #pragma unroll
        for (int r = 0; r < 4; ++r) {
            const int row_l = wr * 64 + m * 16 + l4 * 4 + r;
            const int grow = rowBase + row_l;
            const int prow = grow < HALF_N ? grow + HALF_N : grow - HALF_N;
            float p = 0.0f;
            #pragma unroll
            for (int n = 0; n < 4; ++n) {
                const int gcol = colBase + wc * 64 + n * 16 + l15;
                const float s = (float)acc[m][n][r] * INV_Q2;
                const bool up = (gcol > grow);
                const float e = up ? __expf(s) : 0.0f;
                p += e;
                cs[n] += e;
                if (up && gcol == prow) {      // single upper occurrence
                    poslogit[grow] = s;
                    poslogit[gcol] = s;        // mirrored entry (pos involution)
                }
            }
            p += __shfl_xor(p, 1);
            p += __shfl_xor(p, 2);
            p += __shfl_xor(p, 4);
            p += __shfl_xor(p, 8);
            if (l15 == 0) atomicAdd(&rowsum[row_l], p);
        }
    }
    #pragma unroll
    for (int n = 0; n < 4; ++n) {
        float c = cs[n];
        c += __shfl_xor(c, 16);
        c += __shfl_xor(c, 32);
        if (l4 == 0) atomicAdd(&colsum[wc * 64 + n * 16 + l15], c);
    }
    __syncthreads();
    if (tid < TILE) {
        atomicAdd(&sumexp[rowBase + tid], rowsum[tid]);
        atomicAdd(&sumexp[colBase + tid], colsum[tid]);
    }
#undef LOADT
#undef PHR
}

// Kernel 3: loss = sum_i log(sumexp_i) - poslogit_i
__global__ __launch_bounds__(256) void finalize_kernel(const float* __restrict__ sumexp,
                                                       const float* __restrict__ poslogit,
                                                       float* __restrict__ out) {
    const int i = blockIdx.x * 256 + threadIdx.x;
    float li = logf(sumexp[i]) - poslogit[i];
    #pragma unroll
    for (int off = 32; off >= 1; off >>= 1) li += __shfl_xor(li, off);
    __shared__ float wss[4];
    if ((threadIdx.x & 63) == 0) wss[threadIdx.x >> 6] = li;
    __syncthreads();
    if (threadIdx.x == 0) atomicAdd(out, wss[0] + wss[1] + wss[2] + wss[3]);
}

extern "C" void kernel_launch(void* const* d_in, const int* in_sizes, int n_in,
                              void* d_out, int out_size, void* d_ws, size_t ws_size,
                              hipStream_t stream) {
    const float* X = (const float*)d_in[0];
    float* out = (float*)d_out;

    signed char* XN8 = (signed char*)d_ws;                            // 4 MB int8
    float* sumexp   = (float*)((char*)d_ws + (size_t)NROWS * KD);     // 32 KB
    float* poslogit = sumexp + NROWS;                                 // 32 KB

    normalize_kernel<<<NROWS, 256, 0, stream>>>(X, XN8, sumexp, out);
    gemm_fused_kernel<<<NTRI, 256, 0, stream>>>(XN8, sumexp, poslogit);
    finalize_kernel<<<NROWS / 256, 256, 0, stream>>>(sumexp, poslogit, out);
}

// Round 14
// 50.526 us; speedup vs baseline: 1.6970x; 1.6970x over previous
//
#include <hip/hip_runtime.h>
#include <hip/hip_bf16.h>
#include <math.h>

#define NROWS 8192
#define HALF_N 4096
#define KD 512
#define BM 256                    // block tile rows
#define BN 128                    // block tile cols
#define BK 64                     // i8: 64 B per row per K-tile
#define NKT 8                     // KD / BK
#define INV_Q2 (2.0f / 16129.0f)  // TEMP_INV / 127^2
#define NTILE 1056                // sum over 32 bands of (64 - 2*band)
#define SLOT 24576                // (BM+BN)*BK bytes per LDS slot

typedef __attribute__((ext_vector_type(4))) int i32x4;

// Kernel 1: row-normalize f32 -> int8 (q = round(127*x/||x||)), zero accums.
__global__ __launch_bounds__(256) void normalize_kernel(const float* __restrict__ X,
                                                        signed char* __restrict__ XN8,
                                                        float* __restrict__ sumexp,
                                                        float* __restrict__ out) {
    const int row = blockIdx.x;
    const int tid = threadIdx.x;
    const int gz = row * 256 + tid;
    if (gz < NROWS) sumexp[gz] = 0.0f;
    if (gz == 0) out[0] = 0.0f;

    const float2 v = reinterpret_cast<const float2*>(X + (size_t)row * KD)[tid];
    float ss = v.x * v.x + v.y * v.y;
    #pragma unroll
    for (int off = 32; off >= 1; off >>= 1) ss += __shfl_xor(ss, off);
    __shared__ float wss[4];
    if ((tid & 63) == 0) wss[tid >> 6] = ss;
    __syncthreads();
    const float tot = wss[0] + wss[1] + wss[2] + wss[3];
    const float scale = 127.0f / fmaxf(sqrtf(tot), 1e-6f);
    char2 o;
    o.x = (signed char)__float2int_rn(v.x * scale);
    o.y = (signed char)__float2int_rn(v.y * scale);
    *reinterpret_cast<char2*>(XN8 + (size_t)row * KD + 2 * tid) = o;
}

#define SB __builtin_amdgcn_sched_barrier(0)
#define VMW3 asm volatile("s_waitcnt vmcnt(3)" ::: "memory"); SB
#define VMW0 asm volatile("s_waitcnt vmcnt(0)" ::: "memory"); SB

// Phase t (single-barrier, R10/R11-verified skeleton): 8 swizzled ds_read_b128
// (4 A-rows + 4 B-rows, each a full K=64 i8 fragment) | stage tile t+2
// (3 gload_lds/thread) | lgkm(0) | setprio(1) 16 i8-MFMA setprio(0) |
// TAIL vmcnt | barrier.
// Ledger (3 loads/stage): end-of-phase vmcnt(3) => tile t+1 fully landed,
// t+2 still in flight. Bank swizzle (rounds 9-11, 0 conflicts): 16B chunk
// XOR ((row>>1)&3) on both stage-source and read side.
#define PH(T, STAGE, TAILVM) do {                                              \
    const unsigned char* As = lds + ((T) % 3) * SLOT;                          \
    i32x4 aV[4], bV[4];                                                        \
    _Pragma("unroll")                                                          \
    for (int m = 0; m < 4; ++m) aV[m] = *(const i32x4*)(As + aOff[m]);         \
    _Pragma("unroll")                                                          \
    for (int n = 0; n < 4; ++n) bV[n] = *(const i32x4*)(As + bOff[n]);         \
    SB;                                                                        \
    STAGE;                                                                     \
    SB;                                                                        \
    asm volatile("s_waitcnt lgkmcnt(0)" ::: "memory");                         \
    SB;                                                                        \
    __builtin_amdgcn_s_setprio(1);                                             \
    _Pragma("unroll")                                                          \
    for (int m = 0; m < 4; ++m)                                                \
        _Pragma("unroll")                                                      \
        for (int n = 0; n < 4; ++n)                                            \
            acc[m][n] = __builtin_amdgcn_mfma_i32_16x16x64_i8(                 \
                aV[m], bV[n], acc[m][n], 0, 0, 0);                             \
    __builtin_amdgcn_s_setprio(0);                                             \
    TAILVM;                                                                    \
    __builtin_amdgcn_s_barrier();                                              \
    SB;                                                                        \
  } while (0)

// Band decode: band i (rows 256i..) has tiles j = 2i..63 (128-col tiles).
// prefix(i) = i*(65-i); snake j-order within band for B-panel adjacency.
__device__ __forceinline__ void decode_band(int b, int& bi, int& bj) {
    int i = (int)(32.5f - sqrtf(1056.25f - (float)b));
    while ((i + 1) * (65 - (i + 1)) <= b) ++i;      // float-ulp fixup
    while (i * (65 - i) > b) --i;
    const int r = b - i * (65 - i);
    bi = i;
    bj = 2 * i + ((i & 1) ? (63 - 2 * i - r) : r);
}

// Kernel 2: int8 256x128-tile GEMM (S ~ XN*XN^T / 127^2), 8 waves x (64x64),
// BK=64, 3-slot LDS pipeline, single barrier per phase, counted vmcnt(3).
// Universal epilogue rule: count only gcol > grow, add to rowsum AND colsum
// (handles band-diagonal tiles without a diag/offdiag split).
__global__ __launch_bounds__(512, 4) void gemm_fused_kernel(const signed char* __restrict__ XN8,
                                                            float* __restrict__ sumexp,
                                                            float* __restrict__ poslogit) {
    __shared__ __align__(16) unsigned char lds[3 * SLOT];   // 72 KB -> 2 blocks/CU

    const int b = (blockIdx.x & 7) * (NTILE / 8) + (blockIdx.x >> 3);
    int bi, bj;
    decode_band(b, bi, bj);

    const int rowBase = bi * BM;
    const int colBase = bj * BN;

    const int tid  = threadIdx.x;
    const int lane = tid & 63;
    const int wid  = tid >> 6;          // 0..7
    const int wr   = wid >> 1;          // 0..3  (64 output rows per wave)
    const int wc   = wid & 1;           // 0/1   (64 output cols per wave)
    const int l15  = lane & 15;
    const int l4   = lane >> 4;

    // Hoisted in-slot read offsets (swizzle cp = l4 ^ ((l15>>1)&3); row's
    // multiple-of-16 part contributes 0 to (row>>1)&3).
    const int cp = l4 ^ ((l15 >> 1) & 3);
    int aOff[4], bOff[4];
    #pragma unroll
    for (int m = 0; m < 4; ++m) aOff[m] = (wr * 64 + m * 16 + l15) * 64 + cp * 16;
    #pragma unroll
    for (int n = 0; n < 4; ++n) bOff[n] = 16384 + (wc * 64 + n * 16 + l15) * 64 + cp * 16;

    // Hoisted stage addressing: 1536 chunks/tile (A:1024, B:512); 3 per thread.
    const int rowA0 = tid >> 2;                  // A chunk c = tid
    const int rowA1 = (tid + 512) >> 2;          // A chunk c = tid + 512
    const int sccA0 = (tid & 3) ^ ((rowA0 >> 1) & 3);
    const int sccA1 = (tid & 3) ^ ((rowA1 >> 1) & 3);   // (c+512)&3 == c&3
    const signed char* gA0 = XN8 + (size_t)(rowBase + rowA0) * KD + sccA0 * 16;
    const signed char* gA1 = XN8 + (size_t)(rowBase + rowA1) * KD + sccA1 * 16;
    const signed char* gB0 = XN8 + (size_t)(colBase + rowA0) * KD + sccA0 * 16;
    const int ldsA0 = tid * 16;
    const int ldsA1 = (tid + 512) * 16;
    const int ldsB  = 16384 + tid * 16;

#define STAGE_T(T) do {                                                          \
    unsigned char* slot = lds + ((T) % 3) * SLOT;                                \
    __builtin_amdgcn_global_load_lds(                                            \
        (const __attribute__((address_space(1))) void*)(gA0 + (T) * BK),         \
        (__attribute__((address_space(3))) void*)(slot + ldsA0), 16, 0, 0);      \
    __builtin_amdgcn_global_load_lds(                                            \
        (const __attribute__((address_space(1))) void*)(gA1 + (T) * BK),         \
        (__attribute__((address_space(3))) void*)(slot + ldsA1), 16, 0, 0);      \
    __builtin_amdgcn_global_load_lds(                                            \
        (const __attribute__((address_space(1))) void*)(gB0 + (T) * BK),         \
        (__attribute__((address_space(3))) void*)(slot + ldsB), 16, 0, 0);       \
  } while (0)

    i32x4 acc[4][4] = {};

    // Prologue: tiles 0,1 staged (3 loads/thread each); vmcnt(3)+barrier => t0 ready.
    STAGE_T(0);
    STAGE_T(1);
    VMW3;
    __builtin_amdgcn_s_barrier();

    // Main loop t=0..5: uniform counted-vmcnt phases (3 loads always in flight).
    #pragma unroll
    for (int t = 0; t < NKT - 2; ++t)
        PH(t, STAGE_T(t + 2), VMW3);
    // Tail: t=6 (drain t7's loads), t=7 (nothing outstanding).
    PH(NKT - 2, , VMW0);
    PH(NKT - 1, , );

    __syncthreads();   // protect LDS overlay

    // Epilogue. C/D map: col = l15, row = l4*4 + reg. logit = acc * 2/127^2.
    float* rowsum = (float*)lds;          // [256]
    float* colsum = rowsum + BM;          // [128]
    if (tid < BM) rowsum[tid] = 0.0f;
    if (tid < BN) colsum[tid] = 0.0f;
    __syncthreads();

    float cs[4] = {0.0f, 0.0f, 0.0f, 0.0f};
    #pragma unroll
    for (int m = 0; m < 4; ++m) {
        #pragma unroll
        for (int r = 0; r < 4; ++r) {
            const int row_l = wr * 64 + m * 16 + l4 * 4 + r;
            const int grow = rowBase + row_l;
            const int prow = grow < HALF_N ? grow + HALF_N : grow - HALF_N;
            float p = 0.0f;
            #pragma unroll
            for (int n = 0; n < 4; ++n) {
                const int gcol = colBase + wc * 64 + n * 16 + l15;
                const float s = (float)acc[m][n][r] * INV_Q2;
                const bool up = (gcol > grow);
                const float e = up ? __expf(s) : 0.0f;
                p += e;
                cs[n] += e;
                if (up && gcol == prow) {      // single upper occurrence
                    poslogit[grow] = s;
                    poslogit[gcol] = s;        // mirrored entry (pos involution)
                }
            }
            p += __shfl_xor(p, 1);
            p += __shfl_xor(p, 2);
            p += __shfl_xor(p, 4);
            p += __shfl_xor(p, 8);
            if (l15 == 0) atomicAdd(&rowsum[row_l], p);
        }
    }
    #pragma unroll
    for (int n = 0; n < 4; ++n) {
        float c = cs[n];
        c += __shfl_xor(c, 16);
        c += __shfl_xor(c, 32);
        if (l4 == 0) atomicAdd(&colsum[wc * 64 + n * 16 + l15], c);
    }
    __syncthreads();
    if (tid < BM) atomicAdd(&sumexp[rowBase + tid], rowsum[tid]);
    if (tid < BN) atomicAdd(&sumexp[colBase + tid], colsum[tid]);
#undef STAGE_T
}

// Kernel 3: loss = sum_i log(sumexp_i) - poslogit_i
__global__ __launch_bounds__(256) void finalize_kernel(const float* __restrict__ sumexp,
                                                       const float* __restrict__ poslogit,
                                                       float* __restrict__ out) {
    const int i = blockIdx.x * 256 + threadIdx.x;
    float li = logf(sumexp[i]) - poslogit[i];
    #pragma unroll
    for (int off = 32; off >= 1; off >>= 1) li += __shfl_xor(li, off);
    __shared__ float wss[4];
    if ((threadIdx.x & 63) == 0) wss[threadIdx.x >> 6] = li;
    __syncthreads();
    if (threadIdx.x == 0) atomicAdd(out, wss[0] + wss[1] + wss[2] + wss[3]);
}

extern "C" void kernel_launch(void* const* d_in, const int* in_sizes, int n_in,
                              void* d_out, int out_size, void* d_ws, size_t ws_size,
                              hipStream_t stream) {
    const float* X = (const float*)d_in[0];
    float* out = (float*)d_out;

    signed char* XN8 = (signed char*)d_ws;                            // 4 MB int8
    float* sumexp   = (float*)((char*)d_ws + (size_t)NROWS * KD);     // 32 KB
    float* poslogit = sumexp + NROWS;                                 // 32 KB

    normalize_kernel<<<NROWS, 256, 0, stream>>>(X, XN8, sumexp, out);
    gemm_fused_kernel<<<NTILE, 512, 0, stream>>>(XN8, sumexp, poslogit);
    finalize_kernel<<<NROWS / 256, 256, 0, stream>>>(sumexp, poslogit, out);
}